// Round 14
// baseline (118.392 us; speedup 1.0000x reference)
//
#include <hip/hip_runtime.h>
#include <hip/hip_bf16.h>

// SDPA, causal, b=16 t=2048 d=64. Outputs FP32: d_out = [ out | sm_qk ].
// R14: EQUAL-LENGTH BLOCKS (split-K). Previous causal pairing balanced total
// work but the long block (qb=31, 32 iters) set the per-CU wall at half
// occupancy. Now: flatten the 528 causal tiles per batch, 32 blocks/batch
// get exactly 16-17 consecutive tiles each.
//  K1: lean rowsum (2-MFMA QK^T) -> partial l via atomicAdd to d_ws;
//      zero-fill of the 496 masked tiles interleaved (1 tile/iter).
//  K2: compensated QK^T (qh*kh + ql*kh), P = exp(S)*il direct-stored,
//      PV partials accumulated and flushed per band via unsafeAtomicAdd
//      into memset-zeroed O.
// XCD batch clustering (block i -> XCD i&7 owning batches {2g,2g+1}).
// BAR = lgkm-only barrier. LDS dbuf + depth-2 reg prefetch as R10.

#define BATCHES 16
#define SEQ 2048
#define DIM 64
#define QB 64
#define KT 64
#define NQB (SEQ / QB) /* 32 */
#define KLD 72
#define VLD 72
#define PBLD 72

#define BAR() do { asm volatile("s_waitcnt lgkmcnt(0)" ::: "memory"); \
                   __builtin_amdgcn_s_barrier(); } while (0)

typedef __attribute__((ext_vector_type(8))) short bf16x8;
typedef __attribute__((ext_vector_type(4))) short short4v;
typedef __attribute__((ext_vector_type(4))) float f32x4;

static __device__ __forceinline__ short f2bf(float f) {
    return __builtin_bit_cast(short, __float2bfloat16(f));
}
static __device__ __forceinline__ float bf2f(short s) {
    unsigned int u = ((unsigned int)(unsigned short)s) << 16;
    return __builtin_bit_cast(float, u);
}
static __device__ __forceinline__ bf16x8 pack8(f32x4 a, f32x4 b, float sc) {
    bf16x8 r;
    r[0] = f2bf(a[0]*sc); r[1] = f2bf(a[1]*sc); r[2] = f2bf(a[2]*sc); r[3] = f2bf(a[3]*sc);
    r[4] = f2bf(b[0]*sc); r[5] = f2bf(b[1]*sc); r[6] = f2bf(b[2]*sc); r[7] = f2bf(b[3]*sc);
    return r;
}
static __device__ __forceinline__ void split8(f32x4 a, f32x4 b, float sc,
                                              bf16x8& h, bf16x8& l) {
#pragma unroll
    for (int e = 0; e < 4; ++e) {
        float x = a[e]*sc; short hb = f2bf(x);
        h[e] = hb; l[e] = f2bf(x - bf2f(hb));
    }
#pragma unroll
    for (int e = 0; e < 4; ++e) {
        float x = b[e]*sc; short hb = f2bf(x);
        h[4+e] = hb; l[4+e] = f2bf(x - bf2f(hb));
    }
}

// ---------------- K1: partial rowsums + zero-fill ----------------
__global__ __launch_bounds__(256, 2) void k1_rowsum(
    const float* __restrict__ Qg, const float* __restrict__ Kg,
    float* __restrict__ lW, float* __restrict__ Pg)
{
    const int i = blockIdx.x;
    const int g = i & 7;
    const int j = i >> 3;              // 0..63
    const int b = 2 * g + (j & 1);
    const int c = j >> 1;              // chunk 0..31
    const int t0   = 16 * c + (c < 16 ? c : 16);
    const int tend = t0 + (c < 16 ? 17 : 16);
    int zt         = 15 * c + (c < 16 ? c : 16);
    const int ztend = zt + (c < 16 ? 16 : 15);

    const int tid = threadIdx.x;
    const int lane = tid & 63;
    const int wave = tid >> 6;
    const int lo = lane & 15;
    const int hi = lane >> 4;
    const int sr = tid >> 4;
    const int sc_ = (tid & 15) * 4;

    __shared__ short Khi[2][KT * KLD];

    const float* qB = Qg + (size_t)b * SEQ * DIM;
    const float* kB = Kg + (size_t)b * SEQ * DIM;

    // band trackers: sC = s(qbC+1), s(q) = q(q+1)/2
    int qbC = 0, sC = 1;
    while (t0 >= sC) { ++qbC; sC += qbC + 1; }
    int qbP = 0, sP = 1;               // prefetch tracker (monotonic t)
    auto ktAt = [&](int t) -> int {
        while (t >= sP) { ++qbP; sP += qbP + 1; }
        return t - (sP - (qbP + 1));
    };
    int zqb = 0, zsN = 31;             // zero-list tracker: zs(q+1)

    bf16x8 qa0h, qa1h;
    auto loadQ = [&](int qb) {
        const float* qr = &qB[(size_t)(qb * QB + wave * 16 + lo) * DIM + hi * 8];
        qa0h = pack8(*(const f32x4*)qr,        *(const f32x4*)(qr + 4),  0.125f);
        qa1h = pack8(*(const f32x4*)(qr + 32), *(const f32x4*)(qr + 36), 0.125f);
    };
    loadQ(qbC);

    auto loadK = [&](f32x4* kp, int kt) {
#pragma unroll
        for (int ii = 0; ii < 4; ++ii)
            kp[ii] = *(const f32x4*)&kB[(size_t)(kt * KT + sr + 16 * ii) * DIM + sc_];
    };
    auto stageKhi = [&](int buf, const f32x4* kp) {
#pragma unroll
        for (int ii = 0; ii < 4; ++ii) {
            short4v hh;
#pragma unroll
            for (int e = 0; e < 4; ++e) hh[e] = f2bf(kp[ii][e]);
            *(short4v*)&Khi[buf][(sr + 16 * ii) * KLD + sc_] = hh;
        }
    };

    float rl[4] = {0.f, 0.f, 0.f, 0.f};
    auto flushL = [&](int qb) {
        float r[4] = {rl[0], rl[1], rl[2], rl[3]};
#pragma unroll
        for (int m = 1; m <= 8; m <<= 1)
#pragma unroll
            for (int jx = 0; jx < 4; ++jx) r[jx] += __shfl_xor(r[jx], m, 16);
        if (lo == 0) {
#pragma unroll
            for (int jx = 0; jx < 4; ++jx)
                unsafeAtomicAdd(&lW[(size_t)b * SEQ + qb * QB + wave * 16 + hi * 4 + jx], r[jx]);
        }
        rl[0] = rl[1] = rl[2] = rl[3] = 0.f;
    };
    auto zeroTile = [&]() {
        while (zt >= zsN) { ++zqb; zsN += 31 - zqb; }
        const int ktz = zqb + 1 + (zt - (zsN - (31 - zqb)));
        float* zp = &Pg[((size_t)(b * SEQ) + zqb * QB + (tid >> 2)) * SEQ
                        + ktz * KT + (tid & 3) * 16];
        const f32x4 z = {0.f, 0.f, 0.f, 0.f};
#pragma unroll
        for (int iw = 0; iw < 4; ++iw) *(f32x4*)&zp[4 * iw] = z;
        ++zt;
    };

    f32x4 kp[4];
    loadK(kp, ktAt(t0));
    stageKhi(0, kp);
    if (t0 + 1 < tend) loadK(kp, ktAt(t0 + 1));
    BAR();

    for (int t = t0; t < tend; ++t) {
        const int cur = (t - t0) & 1;
        if (t + 1 < tend) {
            stageKhi(cur ^ 1, kp);
            if (t + 2 < tend) loadK(kp, ktAt(t + 2));
        }
        if (zt < ztend) zeroTile();
        if (t >= sC) { flushL(qbC); ++qbC; sC += qbC + 1; loadQ(qbC); }
        const int kt = t - (sC - (qbC + 1));
        const int nmax = (kt == qbC) ? (wave + 1) : 4;
        for (int n = 0; n < nmax; ++n) {
            bf16x8 kh0 = *(const bf16x8*)&Khi[cur][(16 * n + lo) * KLD + hi * 8];
            bf16x8 kh1 = *(const bf16x8*)&Khi[cur][(16 * n + lo) * KLD + 32 + hi * 8];
            f32x4 acc = {0.f, 0.f, 0.f, 0.f};
            __builtin_amdgcn_s_setprio(1);
            acc = __builtin_amdgcn_mfma_f32_16x16x32_bf16(qa0h, kh0, acc, 0, 0, 0);
            acc = __builtin_amdgcn_mfma_f32_16x16x32_bf16(qa1h, kh1, acc, 0, 0, 0);
            __builtin_amdgcn_s_setprio(0);
            if (kt < qbC) {
#pragma unroll
                for (int jx = 0; jx < 4; ++jx) rl[jx] += __expf(acc[jx]);
            } else {
                const int col = 16 * n + lo;
#pragma unroll
                for (int jx = 0; jx < 4; ++jx)
                    if (col <= wave * 16 + hi * 4 + jx) rl[jx] += __expf(acc[jx]);
            }
        }
        BAR();
    }
    flushL(qbC);
    while (zt < ztend) zeroTile();
}

// ---------------- K2: P emission + O partials ----------------
__global__ __launch_bounds__(256, 2) void k2_emit(
    const float* __restrict__ Qg, const float* __restrict__ Kg,
    const float* __restrict__ Vg, const float* __restrict__ lW,
    float* __restrict__ Og, float* __restrict__ Pg)
{
    const int i = blockIdx.x;
    const int g = i & 7;
    const int j = i >> 3;
    const int b = 2 * g + (j & 1);
    const int c = j >> 1;
    const int t0   = 16 * c + (c < 16 ? c : 16);
    const int tend = t0 + (c < 16 ? 17 : 16);

    const int tid = threadIdx.x;
    const int lane = tid & 63;
    const int wave = tid >> 6;
    const int lo = lane & 15;
    const int hi = lane >> 4;
    const int sr = tid >> 4;
    const int sc_ = (tid & 15) * 4;
    const int vr = (tid >> 4) * 4;

    __shared__ short Khi[2][KT * KLD];
    __shared__ short Vt [2][DIM * VLD];
    __shared__ short Pb [QB * PBLD];

    const float* qB = Qg + (size_t)b * SEQ * DIM;
    const float* kB = Kg + (size_t)b * SEQ * DIM;
    const float* vB = Vg + (size_t)b * SEQ * DIM;

    int qbC = 0, sC = 1;
    while (t0 >= sC) { ++qbC; sC += qbC + 1; }
    int qbP = 0, sP = 1;
    auto ktAt = [&](int t) -> int {
        while (t >= sP) { ++qbP; sP += qbP + 1; }
        return t - (sP - (qbP + 1));
    };

    bf16x8 qa0h, qa0l, qa1h, qa1l;
    float il[4];
    float* prowBase;
    auto bandInit = [&](int qb) {
        const float* qr = &qB[(size_t)(qb * QB + wave * 16 + lo) * DIM + hi * 8];
        split8(*(const f32x4*)qr,        *(const f32x4*)(qr + 4),  0.125f, qa0h, qa0l);
        split8(*(const f32x4*)(qr + 32), *(const f32x4*)(qr + 36), 0.125f, qa1h, qa1l);
#pragma unroll
        for (int jx = 0; jx < 4; ++jx)
            il[jx] = 1.0f / lW[(size_t)b * SEQ + qb * QB + wave * 16 + hi * 4 + jx];
        prowBase = &Pg[((size_t)(b * SEQ) + qb * QB + wave * 16 + hi * 4) * SEQ + lo];
    };
    bandInit(qbC);

    f32x4 o[4];
#pragma unroll
    for (int n = 0; n < 4; ++n) { o[n][0] = 0.f; o[n][1] = 0.f; o[n][2] = 0.f; o[n][3] = 0.f; }
    auto flushO = [&](int qb) {
        float* og = &Og[((size_t)(b * SEQ) + qb * QB + wave * 16 + hi * 4) * DIM + lo];
#pragma unroll
        for (int jx = 0; jx < 4; ++jx)
#pragma unroll
            for (int n = 0; n < 4; ++n)
                unsafeAtomicAdd(&og[jx * DIM + n * 16], o[n][jx]);
#pragma unroll
        for (int n = 0; n < 4; ++n) { o[n][0] = 0.f; o[n][1] = 0.f; o[n][2] = 0.f; o[n][3] = 0.f; }
    };

    auto loadK = [&](f32x4* kp, int kt) {
#pragma unroll
        for (int ii = 0; ii < 4; ++ii)
            kp[ii] = *(const f32x4*)&kB[(size_t)(kt * KT + sr + 16 * ii) * DIM + sc_];
    };
    auto loadV = [&](f32x4* vp, int kt) {
#pragma unroll
        for (int ii = 0; ii < 4; ++ii)
            vp[ii] = *(const f32x4*)&vB[(size_t)(kt * KT + vr + ii) * DIM + sc_];
    };
    auto stageKhi = [&](int buf, const f32x4* kp) {
#pragma unroll
        for (int ii = 0; ii < 4; ++ii) {
            short4v hh;
#pragma unroll
            for (int e = 0; e < 4; ++e) hh[e] = f2bf(kp[ii][e]);
            *(short4v*)&Khi[buf][(sr + 16 * ii) * KLD + sc_] = hh;
        }
    };
    auto stageVt = [&](int buf, const f32x4* vp) {
#pragma unroll
        for (int e = 0; e < 4; ++e) {
            short4v tv;
#pragma unroll
            for (int ii = 0; ii < 4; ++ii) tv[ii] = f2bf(vp[ii][e]);
            *(short4v*)&Vt[buf][(sc_ + e) * VLD + vr] = tv;
        }
    };

    f32x4 kp[4], vp[4];
    {
        const int k0 = ktAt(t0);
        loadK(kp, k0); loadV(vp, k0);
        stageKhi(0, kp); stageVt(0, vp);
        if (t0 + 1 < tend) { const int k1_ = ktAt(t0 + 1); loadK(kp, k1_); loadV(vp, k1_); }
    }
    BAR();

    for (int t = t0; t < tend; ++t) {
        const int cur = (t - t0) & 1;
        if (t + 1 < tend) {
            stageKhi(cur ^ 1, kp);
            stageVt(cur ^ 1, vp);
            if (t + 2 < tend) { const int kn = ktAt(t + 2); loadK(kp, kn); loadV(vp, kn); }
        }
        if (t >= sC) { flushO(qbC); ++qbC; sC += qbC + 1; bandInit(qbC); }
        const int kt = t - (sC - (qbC + 1));

        // QK^T (Q-side compensated) -> P = exp(S)*il : direct store + Pb relay
#pragma unroll
        for (int n = 0; n < 4; ++n) {
            const bool fm = (kt == qbC) && (n > wave);   // wave-uniform
            f32x4 acc = {0.f, 0.f, 0.f, 0.f};
            if (!fm) {
                bf16x8 kh0 = *(const bf16x8*)&Khi[cur][(16 * n + lo) * KLD + hi * 8];
                bf16x8 kh1 = *(const bf16x8*)&Khi[cur][(16 * n + lo) * KLD + 32 + hi * 8];
                __builtin_amdgcn_s_setprio(1);
                acc = __builtin_amdgcn_mfma_f32_16x16x32_bf16(qa0h, kh0, acc, 0, 0, 0);
                acc = __builtin_amdgcn_mfma_f32_16x16x32_bf16(qa1h, kh1, acc, 0, 0, 0);
                acc = __builtin_amdgcn_mfma_f32_16x16x32_bf16(qa0l, kh0, acc, 0, 0, 0);
                acc = __builtin_amdgcn_mfma_f32_16x16x32_bf16(qa1l, kh1, acc, 0, 0, 0);
                __builtin_amdgcn_s_setprio(0);
            }
            const int col = 16 * n + lo;
            float* pcol = prowBase + kt * KT + 16 * n;
#pragma unroll
            for (int jx = 0; jx < 4; ++jx) {
                const int row = wave * 16 + hi * 4 + jx;
                const float p = (!fm && (kt < qbC || col <= row)) ? __expf(acc[jx]) * il[jx] : 0.f;
                pcol[(size_t)jx * SEQ] = p;
                Pb[row * PBLD + col] = f2bf(p);
            }
        }
        // PV: A-frag from Pb (same-wave), B-frag from Vt[cur]
        {
            bf16x8 pa0 = *(const bf16x8*)&Pb[(wave * 16 + lo) * PBLD + hi * 8];
            bf16x8 pa1 = *(const bf16x8*)&Pb[(wave * 16 + lo) * PBLD + 32 + hi * 8];
            __builtin_amdgcn_s_setprio(1);
#pragma unroll
            for (int n = 0; n < 4; ++n) {
                bf16x8 vb0 = *(const bf16x8*)&Vt[cur][(16 * n + lo) * VLD + hi * 8];
                bf16x8 vb1 = *(const bf16x8*)&Vt[cur][(16 * n + lo) * VLD + 32 + hi * 8];
                o[n] = __builtin_amdgcn_mfma_f32_16x16x32_bf16(pa0, vb0, o[n], 0, 0, 0);
                o[n] = __builtin_amdgcn_mfma_f32_16x16x32_bf16(pa1, vb1, o[n], 0, 0, 0);
            }
            __builtin_amdgcn_s_setprio(0);
        }
        BAR();
    }
    flushO(qbC);
}

extern "C" void kernel_launch(void* const* d_in, const int* in_sizes, int n_in,
                              void* d_out, int out_size, void* d_ws, size_t ws_size,
                              hipStream_t stream) {
    const float* q = (const float*)d_in[0];
    const float* k = (const float*)d_in[1];
    const float* v = (const float*)d_in[2];
    float* out  = (float*)d_out;                        // [B,T,D] fp32
    float* smqk = out + (size_t)BATCHES * SEQ * DIM;    // [B,T,T] fp32
    float* lW   = (float*)d_ws;                         // [B,T] fp32 partial sums

    hipMemsetAsync(lW, 0, (size_t)BATCHES * SEQ * sizeof(float), stream);
    hipMemsetAsync(out, 0, (size_t)BATCHES * SEQ * DIM * sizeof(float), stream);
    k1_rowsum<<<NQB * BATCHES, 256, 0, stream>>>(q, k, lW, smqk);
    k2_emit<<<NQB * BATCHES, 256, 0, stream>>>(q, k, v, lW, out, smqk);
}

// Round 15
// 100.337 us; speedup vs baseline: 1.1799x; 1.1799x over previous
//
#include <hip/hip_runtime.h>
#include <hip/hip_bf16.h>

// SDPA, causal, b=16 t=2048 d=64. Outputs FP32: d_out = [ out | sm_qk ].
// R15 = R13 with 8-wave (512-thread) blocks: wave w owns rows (w&3)*16..+16
// and S-cols 32h..32h+32 (h=w>>2, n in {2h,2h+1}). 16 waves/CU (was 8).
//  - T15 pipeline kept: PV(kt-1) before QKT(kt); the end-of-iter barrier
//    orders partner-wave Pb writes -> cross-wave P sharing is free.
//  - Staging role-split: waves 0-3 stage K, waves 4-7 stage V^T.
//  - One-time l merge across column halves via LDS after phase 1.
//  - Q-side-compensated QK^T in phase 2 (qh*kh + ql*kh), lean phase 1.
// XCD batch clustering + causal pairing as R5. BAR = lgkm-only barrier.

#define BATCHES 16
#define SEQ 2048
#define DIM 64
#define QB 64
#define KT 64
#define NQB (SEQ / QB) /* 32 */
#define KLD 72
#define VLD 72
#define PBLD 72

#define BAR() do { asm volatile("s_waitcnt lgkmcnt(0)" ::: "memory"); \
                   __builtin_amdgcn_s_barrier(); } while (0)

typedef __attribute__((ext_vector_type(8))) short bf16x8;
typedef __attribute__((ext_vector_type(4))) short short4v;
typedef __attribute__((ext_vector_type(4))) float f32x4;

static __device__ __forceinline__ short f2bf(float f) {
    return __builtin_bit_cast(short, __float2bfloat16(f));
}
static __device__ __forceinline__ float bf2f(short s) {
    unsigned int u = ((unsigned int)(unsigned short)s) << 16;
    return __builtin_bit_cast(float, u);
}
static __device__ __forceinline__ void split8(f32x4 a, f32x4 b, float sc,
                                              bf16x8& hh, bf16x8& ll) {
#pragma unroll
    for (int e = 0; e < 4; ++e) {
        float x = a[e] * sc; short hb = f2bf(x);
        hh[e] = hb; ll[e] = f2bf(x - bf2f(hb));
    }
#pragma unroll
    for (int e = 0; e < 4; ++e) {
        float x = b[e] * sc; short hb = f2bf(x);
        hh[4 + e] = hb; ll[4 + e] = f2bf(x - bf2f(hb));
    }
}

__global__ __launch_bounds__(512, 2) void sdpa_fused(
    const float* __restrict__ Qg, const float* __restrict__ Kg,
    const float* __restrict__ Vg, float* __restrict__ Og, float* __restrict__ Pg)
{
    const int i = blockIdx.x;
    const int g = i & 7;
    const int j = i >> 3;             // 0..63
    const int b = 2 * g + (j >> 5);
    const int jj = j & 31;
    const int qb = (j < 32) ? jj : (31 - jj);
    const int q0 = qb * QB;

    const int tid = threadIdx.x;
    const int lane = tid & 63;
    const int wave = tid >> 6;        // 0..7
    const int wr = wave & 3;          // row band: rows wr*16..wr*16+15
    const int h  = wave >> 2;         // col half: n in {2h, 2h+1}
    const int n0 = 2 * h;
    const int lo = lane & 15;
    const int hi = lane >> 4;
    const bool kStager = (wave < 4);
    const int stid = kStager ? tid : (tid - 256);   // 0..255 in role group
    const int sr = stid >> 4;
    const int sc_ = (stid & 15) * 4;
    const int vr = (stid >> 4) * 4;

    __shared__ short Khi[2][KT * KLD];   // 18.4 KB
    __shared__ short Vt [3][DIM * VLD];  // 27.6 KB
    __shared__ short Pb [2][QB * PBLD];  // 18.4 KB
    __shared__ float lS [2][QB];         // 0.5 KB

    const float* qB = Qg + (size_t)b * SEQ * DIM;
    const float* kB = Kg + (size_t)b * SEQ * DIM;
    const float* vB = Vg + (size_t)b * SEQ * DIM;

    bf16x8 qa0h, qa0l, qa1h, qa1l;
    {
        const float* qr = &qB[(size_t)(q0 + wr * 16 + lo) * DIM + hi * 8];
        split8(*(const f32x4*)qr,        *(const f32x4*)(qr + 4),  0.125f, qa0h, qa0l);
        split8(*(const f32x4*)(qr + 32), *(const f32x4*)(qr + 36), 0.125f, qa1h, qa1l);
    }

    const int nkt = qb + 1;

    auto loadK = [&](f32x4* kp, int kt) {
#pragma unroll
        for (int ii = 0; ii < 4; ++ii)
            kp[ii] = *(const f32x4*)&kB[(size_t)(kt * KT + sr + 16 * ii) * DIM + sc_];
    };
    auto loadV = [&](f32x4* vp, int kt) {
#pragma unroll
        for (int ii = 0; ii < 4; ++ii)
            vp[ii] = *(const f32x4*)&vB[(size_t)(kt * KT + vr + ii) * DIM + sc_];
    };
    auto stageKhi = [&](int buf, const f32x4* kp) {
#pragma unroll
        for (int ii = 0; ii < 4; ++ii) {
            short4v hh;
#pragma unroll
            for (int e = 0; e < 4; ++e) hh[e] = f2bf(kp[ii][e]);
            *(short4v*)&Khi[buf][(sr + 16 * ii) * KLD + sc_] = hh;
        }
    };
    auto stageVt = [&](int buf, const f32x4* vp) {
#pragma unroll
        for (int e = 0; e < 4; ++e) {
            short4v tv;
#pragma unroll
            for (int ii = 0; ii < 4; ++ii) tv[ii] = f2bf(vp[ii][e]);
            *(short4v*)&Vt[buf][(sc_ + e) * VLD + vr] = tv;
        }
    };

    // ================ phase 1: l partial sums (own col half) ================
    float rl[4] = {0.f, 0.f, 0.f, 0.f};
    {
        f32x4 kp[4];
        if (kStager) {
            loadK(kp, 0);
            stageKhi(0, kp);
            if (nkt > 1) loadK(kp, 1);
        }
        BAR();
        for (int kt = 0; kt < nkt; ++kt) {
            const int cur = kt & 1;
            if (kStager && kt + 1 < nkt) {
                stageKhi(cur ^ 1, kp);
                if (kt + 2 < nkt) loadK(kp, kt + 2);
            }
#pragma unroll
            for (int nn = 0; nn < 2; ++nn) {
                const int n = n0 + nn;
                if (kt == qb && n > wr) continue;   // wave-uniform skip
                bf16x8 kh0 = *(const bf16x8*)&Khi[cur][(16 * n + lo) * KLD + hi * 8];
                bf16x8 kh1 = *(const bf16x8*)&Khi[cur][(16 * n + lo) * KLD + 32 + hi * 8];
                f32x4 acc = {0.f, 0.f, 0.f, 0.f};
                __builtin_amdgcn_s_setprio(1);
                acc = __builtin_amdgcn_mfma_f32_16x16x32_bf16(qa0h, kh0, acc, 0, 0, 0);
                acc = __builtin_amdgcn_mfma_f32_16x16x32_bf16(qa1h, kh1, acc, 0, 0, 0);
                __builtin_amdgcn_s_setprio(0);
                if (kt < qb) {
#pragma unroll
                    for (int jx = 0; jx < 4; ++jx) rl[jx] += __expf(acc[jx]);
                } else {
                    const int col = 16 * n + lo;
#pragma unroll
                    for (int jx = 0; jx < 4; ++jx)
                        if (col <= wr * 16 + hi * 4 + jx) rl[jx] += __expf(acc[jx]);
                }
            }
            BAR();
        }
    }
    // merge the two col-half partials -> il
#pragma unroll
    for (int m = 1; m <= 8; m <<= 1)
#pragma unroll
        for (int jx = 0; jx < 4; ++jx) rl[jx] += __shfl_xor(rl[jx], m, 16);
    if (lo == 0) {
#pragma unroll
        for (int jx = 0; jx < 4; ++jx)
            lS[h][wr * 16 + hi * 4 + jx] = rl[jx];
    }
    BAR();
    float il[4];
#pragma unroll
    for (int jx = 0; jx < 4; ++jx) {
        const int row = wr * 16 + hi * 4 + jx;
        il[jx] = 1.0f / (lS[0][row] + lS[1][row]);
    }

    // ===== phase 2: P = exp(S)*il direct-store + pipelined O = P*V =====
    f32x4 o2[2];
#pragma unroll
    for (int nn = 0; nn < 2; ++nn) { o2[nn][0] = 0.f; o2[nn][1] = 0.f; o2[nn][2] = 0.f; o2[nn][3] = 0.f; }

    float* prowBase = &Pg[((size_t)(b * SEQ) + q0 + wr * 16 + hi * 4) * SEQ + lo];

    {
        f32x4 kp[4], vp[4];
        if (kStager) {
            loadK(kp, 0); stageKhi(0, kp);
            if (nkt > 1) loadK(kp, 1);
        } else {
            loadV(vp, 0); stageVt(0, vp);
            if (nkt > 1) loadV(vp, 1);
        }
        BAR();

        int vstg = 1, vprev = 2;
        for (int kt = 0; kt < nkt; ++kt) {
            const int cur = kt & 1;
            const int pcur = kt & 1;
            if (kt + 1 < nkt) {
                if (kStager) {
                    stageKhi(cur ^ 1, kp);
                    if (kt + 2 < nkt) loadK(kp, kt + 2);
                } else {
                    stageVt(vstg, vp);
                    if (kt + 2 < nkt) loadV(vp, kt + 2);
                }
            }
            // ---- PV(kt-1): partner-wave Pb/Vt ordered by previous BAR ----
            if (kt > 0) {
                bf16x8 pa0 = *(const bf16x8*)&Pb[pcur ^ 1][(wr * 16 + lo) * PBLD + hi * 8];
                bf16x8 pa1 = *(const bf16x8*)&Pb[pcur ^ 1][(wr * 16 + lo) * PBLD + 32 + hi * 8];
                __builtin_amdgcn_s_setprio(1);
#pragma unroll
                for (int nn = 0; nn < 2; ++nn) {
                    const int n = n0 + nn;
                    bf16x8 vb0 = *(const bf16x8*)&Vt[vprev][(16 * n + lo) * VLD + hi * 8];
                    bf16x8 vb1 = *(const bf16x8*)&Vt[vprev][(16 * n + lo) * VLD + 32 + hi * 8];
                    o2[nn] = __builtin_amdgcn_mfma_f32_16x16x32_bf16(pa0, vb0, o2[nn], 0, 0, 0);
                    o2[nn] = __builtin_amdgcn_mfma_f32_16x16x32_bf16(pa1, vb1, o2[nn], 0, 0, 0);
                }
                __builtin_amdgcn_s_setprio(0);
            }
            // ---- QKT(kt) (Q-side compensated): P = exp(S)*il ----
#pragma unroll
            for (int nn = 0; nn < 2; ++nn) {
                const int n = n0 + nn;
                const bool fm = (kt == qb) && (n > wr);   // wave-uniform
                f32x4 acc = {0.f, 0.f, 0.f, 0.f};
                if (!fm) {
                    bf16x8 kh0 = *(const bf16x8*)&Khi[cur][(16 * n + lo) * KLD + hi * 8];
                    bf16x8 kh1 = *(const bf16x8*)&Khi[cur][(16 * n + lo) * KLD + 32 + hi * 8];
                    __builtin_amdgcn_s_setprio(1);
                    acc = __builtin_amdgcn_mfma_f32_16x16x32_bf16(qa0h, kh0, acc, 0, 0, 0);
                    acc = __builtin_amdgcn_mfma_f32_16x16x32_bf16(qa1h, kh1, acc, 0, 0, 0);
                    acc = __builtin_amdgcn_mfma_f32_16x16x32_bf16(qa0l, kh0, acc, 0, 0, 0);
                    acc = __builtin_amdgcn_mfma_f32_16x16x32_bf16(qa1l, kh1, acc, 0, 0, 0);
                    __builtin_amdgcn_s_setprio(0);
                }
                const int col = 16 * n + lo;
                float* pcol = prowBase + kt * KT + 16 * n;
#pragma unroll
                for (int jx = 0; jx < 4; ++jx) {
                    const int row = wr * 16 + hi * 4 + jx;
                    const float p = (!fm && (kt < qb || col <= row)) ? __expf(acc[jx]) * il[jx] : 0.f;
                    pcol[(size_t)jx * SEQ] = p;
                    Pb[pcur][row * PBLD + col] = f2bf(p);
                }
            }
            BAR();
            vprev = (vprev == 2) ? 0 : vprev + 1;
            vstg  = (vstg  == 2) ? 0 : vstg  + 1;
        }
        // ---- epilogue PV(nkt-1): ordered by the loop's final BAR ----
        {
            const int pl = (nkt - 1) & 1;
            const int vl = (nkt - 1) % 3;
            bf16x8 pa0 = *(const bf16x8*)&Pb[pl][(wr * 16 + lo) * PBLD + hi * 8];
            bf16x8 pa1 = *(const bf16x8*)&Pb[pl][(wr * 16 + lo) * PBLD + 32 + hi * 8];
#pragma unroll
            for (int nn = 0; nn < 2; ++nn) {
                const int n = n0 + nn;
                bf16x8 vb0 = *(const bf16x8*)&Vt[vl][(16 * n + lo) * VLD + hi * 8];
                bf16x8 vb1 = *(const bf16x8*)&Vt[vl][(16 * n + lo) * VLD + 32 + hi * 8];
                o2[nn] = __builtin_amdgcn_mfma_f32_16x16x32_bf16(pa0, vb0, o2[nn], 0, 0, 0);
                o2[nn] = __builtin_amdgcn_mfma_f32_16x16x32_bf16(pa1, vb1, o2[nn], 0, 0, 0);
            }
        }
    }

    // ---- zero-fill fully-masked column tiles (exact 0 == ref underflow) ----
    {
        const int r = tid >> 3;
        const int c8 = (tid & 7) * 8;
        float* rowp = &Pg[((size_t)(b * SEQ) + q0 + r) * SEQ + c8];
        const f32x4 z = {0.f, 0.f, 0.f, 0.f};
        for (int cb = nkt * KT; cb < SEQ; cb += KT) {
            *(f32x4*)&rowp[cb] = z;
            *(f32x4*)&rowp[cb + 4] = z;
        }
    }
    // ---- O (already normalized; own col half), fp32 ----
    {
        float* og = &Og[((size_t)(b * SEQ) + q0 + wr * 16 + hi * 4) * DIM + lo];
#pragma unroll
        for (int jx = 0; jx < 4; ++jx)
#pragma unroll
            for (int nn = 0; nn < 2; ++nn)
                og[jx * DIM + (n0 + nn) * 16] = o2[nn][jx];
    }
}

extern "C" void kernel_launch(void* const* d_in, const int* in_sizes, int n_in,
                              void* d_out, int out_size, void* d_ws, size_t ws_size,
                              hipStream_t stream) {
    const float* q = (const float*)d_in[0];
    const float* k = (const float*)d_in[1];
    const float* v = (const float*)d_in[2];
    float* out  = (float*)d_out;                        // [B,T,D] fp32
    float* smqk = out + (size_t)BATCHES * SEQ * DIM;    // [B,T,T] fp32

    sdpa_fused<<<NQB * BATCHES, 512, 0, stream>>>(q, k, v, out, smqk);
}